// Round 5
// baseline (723.781 us; speedup 1.0000x reference)
//
#include <hip/hip_runtime.h>
#include <hip/hip_bf16.h>

#define N_NODESC 100000
#define N_EDGESC 1000000
#define N_QUERYC 100000

typedef short short8 __attribute__((ext_vector_type(8)));
typedef float f32x4 __attribute__((ext_vector_type(4)));

// ---------- dual-dtype load helper (flag: 1 = inputs are bf16, 0 = f32) ----------
__device__ __forceinline__ float ldf(const void* p, int i, int isbf) {
  return isbf ? __bfloat162float(((const __hip_bfloat16*)p)[i])
              : ((const float*)p)[i];
}
__device__ __forceinline__ unsigned short f2b(float x) {
  __hip_bfloat16 h = __float2bfloat16(x);
  return *(unsigned short*)&h;
}
__device__ __forceinline__ float b2f(unsigned int u) {
  return __uint_as_float(u << 16);
}
__device__ __forceinline__ float lo16f(unsigned int u) {
  return __uint_as_float(u << 16);
}
__device__ __forceinline__ float hi16f(unsigned int u) {
  return __uint_as_float(u & 0xffff0000u);
}
__device__ __forceinline__ void gload16(const void* g, void* l) {
  __builtin_amdgcn_global_load_lds(
      (const __attribute__((address_space(1))) void*)g,
      (__attribute__((address_space(3))) void*)l, 16, 0, 0);
}

// ---------- 0: sniff input dtype ----------
__global__ void k_sniff(const void* x, int* flag) {
  __shared__ int cnt;
  int t = threadIdx.x;
  if (t == 0) cnt = 0;
  __syncthreads();
  const unsigned short* h = (const unsigned short*)x;
  int local = 0;
  for (int i = t; i < 4096; i += 256) {
    int e = (h[i] >> 7) & 0xFF;
    if (e >= 107 && e <= 133) local++;
  }
  atomicAdd(&cnt, local);
  __syncthreads();
  if (t == 0) *flag = (cnt >= 3482) ? 1 : 0;
}

// ---------- 1: histogram of dst ----------
__global__ void k_hist(const int* __restrict__ dst, int* __restrict__ cnt, int ne) {
  int e = blockIdx.x * 256 + threadIdx.x;
  if (e < ne) atomicAdd(&cnt[dst[e]], 1);
}

// ---------- 2a: per-chunk exclusive scan ----------
__global__ void k_scan1(const int* __restrict__ cnt, int* __restrict__ off,
                        int* __restrict__ partials, int n) {
  __shared__ int s[1024];
  int t = threadIdx.x;
  int idx = blockIdx.x * 1024 + t;
  int v = (idx < n) ? cnt[idx] : 0;
  s[t] = v;
  __syncthreads();
  for (int d = 1; d < 1024; d <<= 1) {
    int tmp = (t >= d) ? s[t - d] : 0;
    __syncthreads();
    s[t] += tmp;
    __syncthreads();
  }
  if (idx < n) off[idx] = s[t] - v;
  if (t == 1023) partials[blockIdx.x] = s[1023];
}

// ---------- 2b: scan chunk totals ----------
__global__ void k_scan2(const int* __restrict__ partials, int* __restrict__ pref,
                        int* __restrict__ off, int nb, int npos) {
  __shared__ int s[128];
  int t = threadIdx.x;
  int v = (t < nb) ? partials[t] : 0;
  s[t] = v;
  __syncthreads();
  for (int d = 1; d < 128; d <<= 1) {
    int tmp = (t >= d) ? s[t - d] : 0;
    __syncthreads();
    s[t] += tmp;
    __syncthreads();
  }
  if (t < nb) pref[t] = s[t] - v;
  if (t == 127) off[npos] = s[127];
}

// ---------- 2c: apply chunk prefixes ----------
__global__ void k_scan3(int* __restrict__ off, const int* __restrict__ pref,
                        int* __restrict__ cursor, int n) {
  int i = blockIdx.x * 256 + threadIdx.x;
  if (i < n) {
    int o = off[i] + pref[i >> 10];
    off[i] = o;
    cursor[i] = o;
  }
}

// ---------- 3: bucket fill (m = -norm, packed bf16x4 = 8B/edge) ----------
__global__ void k_fill(const int* __restrict__ ei,
                       const void* nr, const void* ni, const void* nj, const void* nk,
                       const int* __restrict__ flagp, int* __restrict__ cursor,
                       int* __restrict__ srcS, uint2* __restrict__ m4b, int ne) {
  int isbf = *flagp;
  int e = blockIdx.x * 256 + threadIdx.x;
  if (e >= ne) return;
  int s = ei[e];
  int d = ei[ne + e];
  int pos = atomicAdd(&cursor[d], 1);
  srcS[pos] = s;
  uint2 m;
  m.x = (unsigned)f2b(-ldf(nr, e, isbf)) | ((unsigned)f2b(-ldf(ni, e, isbf)) << 16);
  m.y = (unsigned)f2b(-ldf(nj, e, isbf)) | ((unsigned)f2b(-ldf(nk, e, isbf)) << 16);
  m4b[pos] = m;
}

// ---------- 3b: interleave inputs -> Xg[node][feat][comp] bf16 ----------
__global__ __launch_bounds__(256) void k_ilv(
    const void* X0, const void* X1, const void* X2, const void* X3,
    const int* __restrict__ flagp, unsigned short* __restrict__ Xg, int n) {
  int isbf = *flagp;
  int lane = threadIdx.x & 63;
  int node = blockIdx.x * 4 + (threadIdx.x >> 6);
  if (node >= n) return;
  int idx = node * 64 + lane;
  unsigned int lo = f2b(ldf(X0, idx, isbf)) | ((unsigned int)f2b(ldf(X1, idx, isbf)) << 16);
  unsigned int hi = f2b(ldf(X2, idx, isbf)) | ((unsigned int)f2b(ldf(X3, idx, isbf)) << 16);
  uint2 g = make_uint2(lo, hi);
  *(uint2*)(Xg + (size_t)node * 256 + lane * 4) = g;
}

// ---------- 4: quaternion aggregation, half-wave 2-edge dwordx4 gathers ----------
// Wave per node. Lane l: half h=l>>5 handles edge p+h; li=l&31 handles features
// 2li, 2li+1 (16B = 2 feats x 4 comps). Cross-half shfl_xor(32) combine at end,
// then in-wave LDS transpose to fragment-major Tf (layout verified R4).
__global__ __launch_bounds__(256) void k_agg(
    const unsigned short* __restrict__ Xg, const int* __restrict__ off,
    const int* __restrict__ srcS, const uint2* __restrict__ m4b,
    unsigned short* __restrict__ Tf, int nnodes) {
  __shared__ unsigned short tl[4][256];
  int lane = threadIdx.x & 63;
  int w = threadIdx.x >> 6;
  int node = blockIdx.x * 4 + w;
  if (node >= nnodes) return;
  int rs = off[node], re = off[node + 1];
  int h = lane >> 5, li = lane & 31;

  float a0r = 0.f, a0i = 0.f, a0j = 0.f, a0k = 0.f;  // feature 2li
  float a1r = 0.f, a1i = 0.f, a1j = 0.f, a1k = 0.f;  // feature 2li+1

  auto step = [&](int e) {
    bool valid = e < re;
    int ec = valid ? e : rs;
    int s = srcS[ec];
    uint2 mp = m4b[ec];
    uint4 g = *(const uint4*)(Xg + (size_t)s * 256 + li * 8);
    float mr = lo16f(mp.x), mi = hi16f(mp.x);
    float mj = lo16f(mp.y), mk = hi16f(mp.y);
    if (!valid) { mr = 0.f; mi = 0.f; mj = 0.f; mk = 0.f; }
    float xr = lo16f(g.x), xi = hi16f(g.x), xj = lo16f(g.y), xk = hi16f(g.y);
    a0r += mr * xr - mi * xi - mj * xj - mk * xk;
    a0i += mr * xi + mi * xr + mj * xk - mk * xj;
    a0j += mr * xj - mi * xk + mj * xr + mk * xi;
    a0k += mr * xk + mi * xj - mj * xi + mk * xr;
    xr = lo16f(g.z); xi = hi16f(g.z); xj = lo16f(g.w); xk = hi16f(g.w);
    a1r += mr * xr - mi * xi - mj * xj - mk * xk;
    a1i += mr * xi + mi * xr + mj * xk - mk * xj;
    a1j += mr * xj - mi * xk + mj * xr + mk * xi;
    a1k += mr * xk + mi * xj - mj * xi + mk * xr;
  };

  int p = rs;
  for (; p + 8 <= re; p += 8) {  // 8 edges, 4 gathers (4KB) in flight
    step(p + h);
    step(p + 2 + h);
    step(p + 4 + h);
    step(p + 6 + h);
  }
  for (; p < re; p += 2) step(p + h);

  // combine halves
  a0r += __shfl_xor(a0r, 32); a0i += __shfl_xor(a0i, 32);
  a0j += __shfl_xor(a0j, 32); a0k += __shfl_xor(a0k, 32);
  a1r += __shfl_xor(a1r, 32); a1i += __shfl_xor(a1i, 32);
  a1j += __shfl_xor(a1j, 32); a1k += __shfl_xor(a1k, 32);

  // tl[w][a*64 + f]: features 2li,2li+1 packed as one dword
  if (h == 0) {
    *(unsigned int*)&tl[w][      2 * li] = (unsigned)f2b(a0r) | ((unsigned)f2b(a1r) << 16);
    *(unsigned int*)&tl[w][ 64 + 2 * li] = (unsigned)f2b(a0i) | ((unsigned)f2b(a1i) << 16);
    *(unsigned int*)&tl[w][128 + 2 * li] = (unsigned)f2b(a0j) | ((unsigned)f2b(a1j) << 16);
    *(unsigned int*)&tl[w][192 + 2 * li] = (unsigned)f2b(a0k) | ((unsigned)f2b(a1k) << 16);
  }
  __builtin_amdgcn_wave_barrier();
  if (lane < 32) {
    uint4 v = *(const uint4*)&tl[w][lane * 8];
    size_t o = (size_t)(node >> 4) * 4096 + (lane >> 2) * 512 + (lane & 3) * 128 +
               (node & 15) * 8;
    *(uint4*)(Tf + o) = v;
  }
}

// ---------- 5: build Weff^T (K-major, bf16) + bias ----------
__global__ void k_weff(const void* W, const void* b, const int* __restrict__ flagp,
                       unsigned short* __restrict__ Wt, float* __restrict__ bcat) {
  int isbf = *flagp;
  int t = blockIdx.x * 256 + threadIdx.x;
  int col = t >> 8;
  int krow = t & 255;
  int a = krow >> 6, kk = krow & 63, c = col >> 6, h = col & 63;
  int w = a ^ c;
  float sgn = ((0x3950 >> (a * 4 + c)) & 1) ? -1.f : 1.f;
  Wt[t] = f2b(sgn * ldf(W, w * 4096 + kk * 64 + h, isbf));
  if (t < 256) bcat[t] = ldf(b, t, isbf);
}

// ---------- 6: single-barrier MFMA GEMM (unchanged from R4) ----------
__global__ __launch_bounds__(256) void k_gemm(
    const unsigned short* __restrict__ A, const unsigned short* __restrict__ Bw,
    const float* __restrict__ bias, int M, int mode,
    unsigned short* __restrict__ XgOut,
    float* __restrict__ P, const void* Cw, const int* __restrict__ flagp) {
  __shared__ unsigned short Bsm[32768];

  int t = threadIdx.x;
  int lane = t & 63;
  int w = t >> 6;
  int l15 = lane & 15, quad = lane >> 4;
  int m0 = blockIdx.x * 128;
  int y = blockIdx.y;

#pragma unroll
  for (int i = 0; i < 16; i++) {
    int p = i * 256 + t;
    int ct = p >> 5;
    int s = (p & 31) ^ (ct & 7);
    int col = (ct >> 5) * 64 + y * 32 + (ct & 31);
    gload16((const char*)Bw + (size_t)col * 512 + s * 16,
            (char*)Bsm + (size_t)(i * 256 + w * 64) * 16);
  }

  short8 av[4][8];
  int tbase = (m0 + (w >> 1) * 64) >> 4;
#pragma unroll
  for (int mi = 0; mi < 4; mi++)
#pragma unroll
    for (int kc = 0; kc < 8; kc++)
      av[mi][kc] = *(const short8*)(A + ((size_t)(tbase + mi) * 8 + kc) * 512 + lane * 8);

  __syncthreads();

  f32x4 acc[4][4];
#pragma unroll
  for (int mi = 0; mi < 4; mi++)
#pragma unroll
    for (int c = 0; c < 4; c++) acc[mi][c] = (f32x4){0.f, 0.f, 0.f, 0.f};

  int ctb = (w & 1) * 16 + l15;
#pragma unroll
  for (int kc = 0; kc < 8; kc++) {
    short8 bv[4];
#pragma unroll
    for (int c = 0; c < 4; c++) {
      int ct = c * 32 + ctb;
      int p = ct * 32 + ((kc * 4 + quad) ^ (ct & 7));
      bv[c] = *(const short8*)&Bsm[p * 8];
    }
#pragma unroll
    for (int mi = 0; mi < 4; mi++)
#pragma unroll
      for (int c = 0; c < 4; c++)
        acc[mi][c] = __builtin_amdgcn_mfma_f32_16x16x32_bf16(av[mi][kc], bv[c], acc[mi][c], 0, 0, 0);
  }

  int fl = y * 32 + (w & 1) * 16 + l15;
  float bias_v[4];
#pragma unroll
  for (int c = 0; c < 4; c++) bias_v[c] = bias[c * 64 + fl];

  if (mode == 0) {
#pragma unroll
    for (int mi = 0; mi < 4; mi++) {
#pragma unroll
      for (int r = 0; r < 4; r++) {
        int node = m0 + (w >> 1) * 64 + mi * 16 + quad * 4 + r;
        unsigned int lo = f2b(fmaxf(acc[mi][0][r] + bias_v[0], 0.f)) |
                          ((unsigned int)f2b(fmaxf(acc[mi][1][r] + bias_v[1], 0.f)) << 16);
        unsigned int hi = f2b(fmaxf(acc[mi][2][r] + bias_v[2], 0.f)) |
                          ((unsigned int)f2b(fmaxf(acc[mi][3][r] + bias_v[3], 0.f)) << 16);
        *(uint2*)(XgOut + (size_t)node * 256 + fl * 4) = make_uint2(lo, hi);
      }
    }
  } else {
    int isbf = *flagp;
    float cw[4][4];
#pragma unroll
    for (int c = 0; c < 4; c++)
#pragma unroll
      for (int d = 0; d < 2; d++)
#pragma unroll
        for (int e = 0; e < 2; e++)
          cw[c][e + 2 * d] = ldf(Cw, d * 512 + c * 128 + e * 64 + fl, isbf);
#pragma unroll
    for (int mi = 0; mi < 4; mi++) {
#pragma unroll
      for (int r = 0; r < 4; r++) {
        int node = m0 + (w >> 1) * 64 + mi * 16 + quad * 4 + r;
        float pd0 = 0.f, pd1 = 0.f, pd2 = 0.f, pd3 = 0.f;
#pragma unroll
        for (int c = 0; c < 4; c++) {
          float v = fmaxf(acc[mi][c][r] + bias_v[c], 0.f);
          pd0 += v * cw[c][0];
          pd1 += v * cw[c][1];
          pd2 += v * cw[c][2];
          pd3 += v * cw[c][3];
        }
#pragma unroll
        for (int o = 1; o < 16; o <<= 1) {
          pd0 += __shfl_xor(pd0, o);
          pd1 += __shfl_xor(pd1, o);
          pd2 += __shfl_xor(pd2, o);
          pd3 += __shfl_xor(pd3, o);
        }
        if (l15 == 0 && node < M) {
          atomicAdd(&P[node * 4 + 0], pd0);
          atomicAdd(&P[node * 4 + 1], pd1);
          atomicAdd(&P[node * 4 + 2], pd2);
          atomicAdd(&P[node * 4 + 3], pd3);
        }
      }
    }
  }
}

// ---------- 8: per-query logits + log_softmax ----------
__global__ void k_query(const int* __restrict__ qe, const float* __restrict__ P,
                        const void* Cb, const int* __restrict__ flagp,
                        void* out, int nq) {
  int isbf = *flagp;
  int q = blockIdx.x * 256 + threadIdx.x;
  if (q >= nq) return;
  int q0 = qe[q * 2], q1 = qe[q * 2 + 1];
  float l0 = P[q0 * 4 + 0] + P[q1 * 4 + 1] + ldf(Cb, 0, isbf);
  float l1 = P[q0 * 4 + 2] + P[q1 * 4 + 3] + ldf(Cb, 1, isbf);
  float m = fmaxf(l0, l1);
  float lse = m + logf(expf(l0 - m) + expf(l1 - m));
  float o0 = l0 - lse, o1 = l1 - lse;
  if (isbf) {
    __hip_bfloat16* o = (__hip_bfloat16*)out;
    o[q * 2] = __float2bfloat16(o0);
    o[q * 2 + 1] = __float2bfloat16(o1);
  } else {
    float* o = (float*)out;
    o[q * 2] = o0;
    o[q * 2 + 1] = o1;
  }
}

extern "C" void kernel_launch(void* const* d_in, const int* in_sizes, int n_in,
                              void* d_out, int out_size, void* d_ws, size_t ws_size,
                              hipStream_t stream) {
  const int N = N_NODESC, NE = N_EDGESC, NQ = N_QUERYC;
  const int NPAD = 100224;  // >= 782*128 = 100096

  char* w = (char*)d_ws;
  auto alloc = [&](size_t bytes) -> void* {
    void* p = (void*)w;
    w += (bytes + 255) & ~(size_t)255;
    return p;
  };
  int* flag       = (int*)alloc(4);
  int* offsets    = (int*)alloc((size_t)(N + 1) * 4);
  int* cursor     = (int*)alloc((size_t)N * 4);
  int* partials   = (int*)alloc(128 * 4);
  int* pref       = (int*)alloc(128 * 4);
  int* srcS       = (int*)alloc((size_t)NE * 4);
  uint2* m4b      = (uint2*)alloc((size_t)NE * 8);
  unsigned short* Tf   = (unsigned short*)alloc((size_t)NPAD * 256 * 2);
  unsigned short* Xg   = (unsigned short*)alloc((size_t)NPAD * 256 * 2);
  unsigned short* Wt   = (unsigned short*)alloc(256 * 256 * 2);
  float* bcat     = (float*)alloc(256 * 4);
  float* P        = (float*)alloc((size_t)N * 4 * 4);
  (void)ws_size; (void)n_in; (void)in_sizes; (void)out_size;

  const int* ei = (const int*)d_in[8];

  k_sniff<<<1, 256, 0, stream>>>(d_in[0], flag);

  // CSR build
  hipMemsetAsync(cursor, 0, (size_t)N * 4, stream);
  hipMemsetAsync(P, 0, (size_t)N * 16, stream);
  k_hist<<<(NE + 255) / 256, 256, 0, stream>>>(ei + NE, cursor, NE);
  k_scan1<<<(N + 1023) / 1024, 1024, 0, stream>>>(cursor, offsets, partials, N);
  k_scan2<<<1, 128, 0, stream>>>(partials, pref, offsets, (N + 1023) / 1024, N);
  k_scan3<<<(N + 255) / 256, 256, 0, stream>>>(offsets, pref, cursor, N);
  k_fill<<<(NE + 255) / 256, 256, 0, stream>>>(ei, d_in[4], d_in[5], d_in[6], d_in[7],
                                               flag, cursor, srcS, m4b, NE);

  // layer-1 gather source
  k_ilv<<<(N + 3) / 4, 256, 0, stream>>>(d_in[0], d_in[1], d_in[2], d_in[3], flag, Xg, N);

  dim3 ggrid((N + 127) / 128, 2);

  // layer 1
  k_agg<<<(N + 3) / 4, 256, 0, stream>>>(Xg, offsets, srcS, m4b, Tf, N);
  k_weff<<<256, 256, 0, stream>>>(d_in[10], d_in[11], flag, Wt, bcat);
  k_gemm<<<ggrid, 256, 0, stream>>>(Tf, Wt, bcat, N, 0, Xg, nullptr, nullptr, flag);

  // layer 2 (+fused readout partial dots)
  k_agg<<<(N + 3) / 4, 256, 0, stream>>>(Xg, offsets, srcS, m4b, Tf, N);
  k_weff<<<256, 256, 0, stream>>>(d_in[12], d_in[13], flag, Wt, bcat);
  k_gemm<<<ggrid, 256, 0, stream>>>(Tf, Wt, bcat, N, 1, nullptr, P, d_in[14], flag);

  // queries
  k_query<<<(NQ + 255) / 256, 256, 0, stream>>>((const int*)d_in[9], P, d_in[15],
                                                flag, d_out, NQ);
}

// Round 6
// 582.268 us; speedup vs baseline: 1.2430x; 1.2430x over previous
//
#include <hip/hip_runtime.h>
#include <hip/hip_bf16.h>

#define N_NODESC 100000
#define N_EDGESC 1000000
#define N_QUERYC 100000

typedef short short8 __attribute__((ext_vector_type(8)));
typedef float f32x4 __attribute__((ext_vector_type(4)));

// ---------- dual-dtype load helper (flag: 1 = inputs are bf16, 0 = f32) ----------
__device__ __forceinline__ float ldf(const void* p, int i, int isbf) {
  return isbf ? __bfloat162float(((const __hip_bfloat16*)p)[i])
              : ((const float*)p)[i];
}
__device__ __forceinline__ unsigned short f2b(float x) {
  __hip_bfloat16 h = __float2bfloat16(x);
  return *(unsigned short*)&h;
}
__device__ __forceinline__ float b2f(unsigned int u) {
  return __uint_as_float(u << 16);
}
__device__ __forceinline__ void gload16(const void* g, void* l) {
  __builtin_amdgcn_global_load_lds(
      (const __attribute__((address_space(1))) void*)g,
      (__attribute__((address_space(3))) void*)l, 16, 0, 0);
}

// ---------- 0: sniff input dtype ----------
__global__ void k_sniff(const void* x, int* flag) {
  __shared__ int cnt;
  int t = threadIdx.x;
  if (t == 0) cnt = 0;
  __syncthreads();
  const unsigned short* h = (const unsigned short*)x;
  int local = 0;
  for (int i = t; i < 4096; i += 256) {
    int e = (h[i] >> 7) & 0xFF;
    if (e >= 107 && e <= 133) local++;
  }
  atomicAdd(&cnt, local);
  __syncthreads();
  if (t == 0) *flag = (cnt >= 3482) ? 1 : 0;
}

// ---------- 1: histogram of dst ----------
__global__ void k_hist(const int* __restrict__ dst, int* __restrict__ cnt, int ne) {
  int e = blockIdx.x * 256 + threadIdx.x;
  if (e < ne) atomicAdd(&cnt[dst[e]], 1);
}

// ---------- 2a: per-chunk exclusive scan ----------
__global__ void k_scan1(const int* __restrict__ cnt, int* __restrict__ off,
                        int* __restrict__ partials, int n) {
  __shared__ int s[1024];
  int t = threadIdx.x;
  int idx = blockIdx.x * 1024 + t;
  int v = (idx < n) ? cnt[idx] : 0;
  s[t] = v;
  __syncthreads();
  for (int d = 1; d < 1024; d <<= 1) {
    int tmp = (t >= d) ? s[t - d] : 0;
    __syncthreads();
    s[t] += tmp;
    __syncthreads();
  }
  if (idx < n) off[idx] = s[t] - v;
  if (t == 1023) partials[blockIdx.x] = s[1023];
}

// ---------- 2b: scan chunk totals ----------
__global__ void k_scan2(const int* __restrict__ partials, int* __restrict__ pref,
                        int* __restrict__ off, int nb, int npos) {
  __shared__ int s[128];
  int t = threadIdx.x;
  int v = (t < nb) ? partials[t] : 0;
  s[t] = v;
  __syncthreads();
  for (int d = 1; d < 128; d <<= 1) {
    int tmp = (t >= d) ? s[t - d] : 0;
    __syncthreads();
    s[t] += tmp;
    __syncthreads();
  }
  if (t < nb) pref[t] = s[t] - v;
  if (t == 127) off[npos] = s[127];
}

// ---------- 2c: apply chunk prefixes ----------
__global__ void k_scan3(int* __restrict__ off, const int* __restrict__ pref,
                        int* __restrict__ cursor, int n) {
  int i = blockIdx.x * 256 + threadIdx.x;
  if (i < n) {
    int o = off[i] + pref[i >> 10];
    off[i] = o;
    cursor[i] = o;
  }
}

// ---------- 3: bucket fill (m = -norm, packed bf16x4 = 8B/edge) ----------
__global__ void k_fill(const int* __restrict__ ei,
                       const void* nr, const void* ni, const void* nj, const void* nk,
                       const int* __restrict__ flagp, int* __restrict__ cursor,
                       int* __restrict__ srcS, uint2* __restrict__ m4b, int ne) {
  int isbf = *flagp;
  int e = blockIdx.x * 256 + threadIdx.x;
  if (e >= ne) return;
  int s = ei[e];
  int d = ei[ne + e];
  int pos = atomicAdd(&cursor[d], 1);
  srcS[pos] = s;
  uint2 m;
  m.x = (unsigned)f2b(-ldf(nr, e, isbf)) | ((unsigned)f2b(-ldf(ni, e, isbf)) << 16);
  m.y = (unsigned)f2b(-ldf(nj, e, isbf)) | ((unsigned)f2b(-ldf(nk, e, isbf)) << 16);
  m4b[pos] = m;
}

// ---------- 3b: interleave inputs -> Xg[node][feat][comp] bf16 ----------
__global__ __launch_bounds__(256) void k_ilv(
    const void* X0, const void* X1, const void* X2, const void* X3,
    const int* __restrict__ flagp, unsigned short* __restrict__ Xg, int n) {
  int isbf = *flagp;
  int lane = threadIdx.x & 63;
  int node = blockIdx.x * 4 + (threadIdx.x >> 6);
  if (node >= n) return;
  int idx = node * 64 + lane;
  unsigned int lo = f2b(ldf(X0, idx, isbf)) | ((unsigned int)f2b(ldf(X1, idx, isbf)) << 16);
  unsigned int hi = f2b(ldf(X2, idx, isbf)) | ((unsigned int)f2b(ldf(X3, idx, isbf)) << 16);
  uint2 g = make_uint2(lo, hi);
  *(uint2*)(Xg + (size_t)node * 256 + lane * 4) = g;
}

// ---------- 4: quaternion aggregation (wave/node, uint2 gather, unroll 8) ----------
// R4 structure (36 VGPR, best measured req-rate) + 8 independent gathers in
// flight + launch_bounds(256,8) to pin max occupancy.
// Output: fragment-major Tf[(node>>4)*4096 + kc*512 + q*128 + (node&15)*8 + j]
__global__ __launch_bounds__(256, 8) void k_agg(
    const unsigned short* __restrict__ Xg, const int* __restrict__ off,
    const int* __restrict__ srcS, const uint2* __restrict__ m4b,
    unsigned short* __restrict__ Tf, int nnodes) {
  __shared__ unsigned short tl[4][256];
  int lane = threadIdx.x & 63;
  int w = threadIdx.x >> 6;
  int node = blockIdx.x * 4 + w;
  if (node >= nnodes) return;
  int rs = off[node], re = off[node + 1];
  float tr = 0.f, ti = 0.f, tj = 0.f, tk = 0.f;

  auto qacc = [&](uint2 g, uint2 mp) {
    float mr = b2f(mp.x & 0xffffu), mi = __uint_as_float(mp.x & 0xffff0000u);
    float mj = b2f(mp.y & 0xffffu), mk = __uint_as_float(mp.y & 0xffff0000u);
    float xr = b2f(g.x & 0xffffu), xi = __uint_as_float(g.x & 0xffff0000u);
    float xj = b2f(g.y & 0xffffu), xk = __uint_as_float(g.y & 0xffff0000u);
    tr += mr * xr - mi * xi - mj * xj - mk * xk;
    ti += mr * xi + mi * xr + mj * xk - mk * xj;
    tj += mr * xj - mi * xk + mj * xr + mk * xi;
    tk += mr * xk + mi * xj - mj * xi + mk * xr;
  };

  int e = rs;
  for (; e + 8 <= re; e += 8) {
    uint2 g[8], mm[8];
#pragma unroll
    for (int u = 0; u < 8; u++) {
      int s = srcS[e + u];
      mm[u] = m4b[e + u];
      g[u] = *(const uint2*)(Xg + (size_t)s * 256 + lane * 4);
    }
#pragma unroll
    for (int u = 0; u < 8; u++) qacc(g[u], mm[u]);
  }
  for (; e < re; ++e) {
    uint2 g0 = *(const uint2*)(Xg + (size_t)srcS[e] * 256 + lane * 4);
    qacc(g0, m4b[e]);
  }

  // in-wave transpose: lane=f holds 4 comps -> 16B chunks in k-order
  tl[w][lane] = f2b(tr);
  tl[w][64 + lane] = f2b(ti);
  tl[w][128 + lane] = f2b(tj);
  tl[w][192 + lane] = f2b(tk);
  __builtin_amdgcn_wave_barrier();
  if (lane < 32) {
    uint4 v = *(const uint4*)&tl[w][lane * 8];
    size_t o = (size_t)(node >> 4) * 4096 + (lane >> 2) * 512 + (lane & 3) * 128 +
               (node & 15) * 8;
    *(uint4*)(Tf + o) = v;
  }
}

// ---------- 5: build swizzled k-major base matrices Wq (4x64x64, 32KB) + bias ----------
// Wq[(w4*64 + h)*64 + ((kk>>3)^(h&7))*8 + (kk&7)] = W[w4][kk][h]  (bf16, NO sign)
__global__ void k_weff(const void* W, const void* b, const int* __restrict__ flagp,
                       unsigned short* __restrict__ Wq, float* __restrict__ bcat) {
  int isbf = *flagp;
  int t = blockIdx.x * 256 + threadIdx.x;  // 0..16383
  int w4 = t >> 12;
  int h = (t >> 6) & 63;
  int kk = t & 63;
  int s = (kk >> 3) ^ (h & 7);
  Wq[(w4 * 64 + h) * 64 + s * 8 + (kk & 7)] = f2b(ldf(W, w4 * 4096 + kk * 64 + h, isbf));
  if (t < 256) bcat[t] = ldf(b, t, isbf);
}

// ---------- 6: quaternion-structured MFMA GEMM, one barrier ----------
// grid (ceil(M/64), 1); block 256 = 4 waves. Block = 64 rows x all 256 cols.
// B never restaged: the 4 base matrices (32KB) staged once; sign sgn(a,c)
// applied by XOR on the fragment. Wave w: rows (w>>1)*32..+32, col half
// h in [(w&1)*32, +32); all 4 components c per lane -> packed uint2 store.
// A frags read direct from fragment-major Tf AFTER the barrier (no drain).
__global__ __launch_bounds__(256, 2) void k_gemm(
    const unsigned short* __restrict__ A, const unsigned short* __restrict__ Wq,
    const float* __restrict__ bias, int M, int mode,
    unsigned short* __restrict__ XgOut,
    float* __restrict__ P, const void* Cw, const int* __restrict__ flagp) {
  __shared__ unsigned short Wsm[16384];  // 32 KB

  int t = threadIdx.x;
  int lane = t & 63;
  int w = t >> 6;
  int l15 = lane & 15, quad = lane >> 4;
  int m0 = blockIdx.x * 64;
  int hh = (w & 1) * 32;

  // stage base matrices (identity copy of pre-swizzled table)
#pragma unroll
  for (int i = 0; i < 8; i++)
    gload16((const char*)Wq + (size_t)(i * 256 + t) * 16,
            (char*)Wsm + (size_t)(i * 256 + w * 64) * 16);
  __syncthreads();

  // A fragments issued after the barrier: fine-grained vmcnt, no drain
  short8 av[2][8];
  int n16 = blockIdx.x * 4 + (w >> 1) * 2;
#pragma unroll
  for (int mi = 0; mi < 2; mi++)
#pragma unroll
    for (int kc = 0; kc < 8; kc++)
      av[mi][kc] = *(const short8*)(A + (size_t)(n16 + mi) * 4096 + kc * 512 + lane * 8);

  f32x4 acc[2][4][2];
#pragma unroll
  for (int mi = 0; mi < 2; mi++)
#pragma unroll
    for (int c = 0; c < 4; c++)
#pragma unroll
      for (int hb = 0; hb < 2; hb++) acc[mi][c][hb] = (f32x4){0.f, 0.f, 0.f, 0.f};

#pragma unroll
  for (int kc = 0; kc < 8; kc++) {
    int a = kc >> 1;
    short8 bv[4][2];
#pragma unroll
    for (int c = 0; c < 4; c++) {
      int w4 = a ^ c;
      int neg = (0x3950 >> (a * 4 + c)) & 1;
#pragma unroll
      for (int hb = 0; hb < 2; hb++) {
        int h = hh + hb * 16 + l15;
        int lc = ((kc & 1) * 4 + quad) ^ (l15 & 7);
        short8 bb = *(const short8*)&Wsm[(w4 * 64 + h) * 64 + lc * 8];
        if (neg) {
          uint4 u = *(uint4*)&bb;
          u.x ^= 0x80008000u; u.y ^= 0x80008000u;
          u.z ^= 0x80008000u; u.w ^= 0x80008000u;
          bb = *(short8*)&u;
        }
        bv[c][hb] = bb;
      }
    }
#pragma unroll
    for (int mi = 0; mi < 2; mi++)
#pragma unroll
      for (int c = 0; c < 4; c++)
#pragma unroll
        for (int hb = 0; hb < 2; hb++)
          acc[mi][c][hb] =
              __builtin_amdgcn_mfma_f32_16x16x32_bf16(av[mi][kc], bv[c][hb], acc[mi][c][hb], 0, 0, 0);
  }

  float bias_v[4][2];
#pragma unroll
  for (int c = 0; c < 4; c++)
#pragma unroll
    for (int hb = 0; hb < 2; hb++) bias_v[c][hb] = bias[c * 64 + hh + hb * 16 + l15];

  if (mode == 0) {
#pragma unroll
    for (int mi = 0; mi < 2; mi++) {
#pragma unroll
      for (int hb = 0; hb < 2; hb++) {
#pragma unroll
        for (int r = 0; r < 4; r++) {
          int node = m0 + (w >> 1) * 32 + mi * 16 + quad * 4 + r;
          unsigned int lo =
              f2b(fmaxf(acc[mi][0][hb][r] + bias_v[0][hb], 0.f)) |
              ((unsigned int)f2b(fmaxf(acc[mi][1][hb][r] + bias_v[1][hb], 0.f)) << 16);
          unsigned int hi =
              f2b(fmaxf(acc[mi][2][hb][r] + bias_v[2][hb], 0.f)) |
              ((unsigned int)f2b(fmaxf(acc[mi][3][hb][r] + bias_v[3][hb], 0.f)) << 16);
          *(uint2*)(XgOut + (size_t)node * 256 + (hh + hb * 16 + l15) * 4) =
              make_uint2(lo, hi);
        }
      }
    }
  } else {
    int isbf = *flagp;
    float cw[4][2][4];
#pragma unroll
    for (int c = 0; c < 4; c++)
#pragma unroll
      for (int hb = 0; hb < 2; hb++) {
        int h = hh + hb * 16 + l15;
#pragma unroll
        for (int d = 0; d < 2; d++)
#pragma unroll
          for (int e = 0; e < 2; e++)
            cw[c][hb][e + 2 * d] = ldf(Cw, d * 512 + c * 128 + e * 64 + h, isbf);
      }
#pragma unroll
    for (int mi = 0; mi < 2; mi++) {
#pragma unroll
      for (int r = 0; r < 4; r++) {
        int node = m0 + (w >> 1) * 32 + mi * 16 + quad * 4 + r;
        float pd0 = 0.f, pd1 = 0.f, pd2 = 0.f, pd3 = 0.f;
#pragma unroll
        for (int c = 0; c < 4; c++)
#pragma unroll
          for (int hb = 0; hb < 2; hb++) {
            float v = fmaxf(acc[mi][c][hb][r] + bias_v[c][hb], 0.f);
            pd0 += v * cw[c][hb][0];
            pd1 += v * cw[c][hb][1];
            pd2 += v * cw[c][hb][2];
            pd3 += v * cw[c][hb][3];
          }
#pragma unroll
        for (int o = 1; o < 16; o <<= 1) {
          pd0 += __shfl_xor(pd0, o);
          pd1 += __shfl_xor(pd1, o);
          pd2 += __shfl_xor(pd2, o);
          pd3 += __shfl_xor(pd3, o);
        }
        if (l15 == 0 && node < M) {
          atomicAdd(&P[node * 4 + 0], pd0);
          atomicAdd(&P[node * 4 + 1], pd1);
          atomicAdd(&P[node * 4 + 2], pd2);
          atomicAdd(&P[node * 4 + 3], pd3);
        }
      }
    }
  }
}

// ---------- 8: per-query logits + log_softmax ----------
__global__ void k_query(const int* __restrict__ qe, const float* __restrict__ P,
                        const void* Cb, const int* __restrict__ flagp,
                        void* out, int nq) {
  int isbf = *flagp;
  int q = blockIdx.x * 256 + threadIdx.x;
  if (q >= nq) return;
  int q0 = qe[q * 2], q1 = qe[q * 2 + 1];
  float l0 = P[q0 * 4 + 0] + P[q1 * 4 + 1] + ldf(Cb, 0, isbf);
  float l1 = P[q0 * 4 + 2] + P[q1 * 4 + 3] + ldf(Cb, 1, isbf);
  float m = fmaxf(l0, l1);
  float lse = m + logf(expf(l0 - m) + expf(l1 - m));
  float o0 = l0 - lse, o1 = l1 - lse;
  if (isbf) {
    __hip_bfloat16* o = (__hip_bfloat16*)out;
    o[q * 2] = __float2bfloat16(o0);
    o[q * 2 + 1] = __float2bfloat16(o1);
  } else {
    float* o = (float*)out;
    o[q * 2] = o0;
    o[q * 2 + 1] = o1;
  }
}

extern "C" void kernel_launch(void* const* d_in, const int* in_sizes, int n_in,
                              void* d_out, int out_size, void* d_ws, size_t ws_size,
                              hipStream_t stream) {
  const int N = N_NODESC, NE = N_EDGESC, NQ = N_QUERYC;
  const int NPAD = 100224;  // >= 1563*64 = 100032

  char* w = (char*)d_ws;
  auto alloc = [&](size_t bytes) -> void* {
    void* p = (void*)w;
    w += (bytes + 255) & ~(size_t)255;
    return p;
  };
  int* flag       = (int*)alloc(4);
  int* offsets    = (int*)alloc((size_t)(N + 1) * 4);
  int* cursor     = (int*)alloc((size_t)N * 4);
  int* partials   = (int*)alloc(128 * 4);
  int* pref       = (int*)alloc(128 * 4);
  int* srcS       = (int*)alloc((size_t)NE * 4);
  uint2* m4b      = (uint2*)alloc((size_t)NE * 8);
  unsigned short* Tf = (unsigned short*)alloc((size_t)NPAD * 256 * 2);
  unsigned short* Xg = (unsigned short*)alloc((size_t)NPAD * 256 * 2);
  unsigned short* Wq = (unsigned short*)alloc(16384 * 2);
  float* bcat     = (float*)alloc(256 * 4);
  float* P        = (float*)alloc((size_t)N * 4 * 4);
  (void)ws_size; (void)n_in; (void)in_sizes; (void)out_size;

  const int* ei = (const int*)d_in[8];

  k_sniff<<<1, 256, 0, stream>>>(d_in[0], flag);

  // CSR build
  hipMemsetAsync(cursor, 0, (size_t)N * 4, stream);
  hipMemsetAsync(P, 0, (size_t)N * 16, stream);
  k_hist<<<(NE + 255) / 256, 256, 0, stream>>>(ei + NE, cursor, NE);
  k_scan1<<<(N + 1023) / 1024, 1024, 0, stream>>>(cursor, offsets, partials, N);
  k_scan2<<<1, 128, 0, stream>>>(partials, pref, offsets, (N + 1023) / 1024, N);
  k_scan3<<<(N + 255) / 256, 256, 0, stream>>>(offsets, pref, cursor, N);
  k_fill<<<(NE + 255) / 256, 256, 0, stream>>>(ei, d_in[4], d_in[5], d_in[6], d_in[7],
                                               flag, cursor, srcS, m4b, NE);

  // layer-1 gather source
  k_ilv<<<(N + 3) / 4, 256, 0, stream>>>(d_in[0], d_in[1], d_in[2], d_in[3], flag, Xg, N);

  int ggrid = (N + 63) / 64;

  // layer 1
  k_agg<<<(N + 3) / 4, 256, 0, stream>>>(Xg, offsets, srcS, m4b, Tf, N);
  k_weff<<<64, 256, 0, stream>>>(d_in[10], d_in[11], flag, Wq, bcat);
  k_gemm<<<ggrid, 256, 0, stream>>>(Tf, Wq, bcat, N, 0, Xg, nullptr, nullptr, flag);

  // layer 2 (+fused readout partial dots)
  k_agg<<<(N + 3) / 4, 256, 0, stream>>>(Xg, offsets, srcS, m4b, Tf, N);
  k_weff<<<64, 256, 0, stream>>>(d_in[12], d_in[13], flag, Wq, bcat);
  k_gemm<<<ggrid, 256, 0, stream>>>(Tf, Wq, bcat, N, 1, nullptr, P, d_in[14], flag);

  // queries
  k_query<<<(NQ + 255) / 256, 256, 0, stream>>>((const int*)d_in[9], P, d_in[15],
                                                flag, d_out, NQ);
}

// Round 7
// 549.896 us; speedup vs baseline: 1.3162x; 1.0589x over previous
//
#include <hip/hip_runtime.h>
#include <hip/hip_bf16.h>

#define N_NODESC 100000
#define N_EDGESC 1000000
#define N_QUERYC 100000

typedef short short8 __attribute__((ext_vector_type(8)));
typedef float f32x4 __attribute__((ext_vector_type(4)));

// ---------- dual-dtype load helper (flag: 1 = inputs are bf16, 0 = f32) ----------
__device__ __forceinline__ float ldf(const void* p, int i, int isbf) {
  return isbf ? __bfloat162float(((const __hip_bfloat16*)p)[i])
              : ((const float*)p)[i];
}
__device__ __forceinline__ unsigned short f2b(float x) {
  __hip_bfloat16 h = __float2bfloat16(x);
  return *(unsigned short*)&h;
}
__device__ __forceinline__ float b2f(unsigned int u) {
  return __uint_as_float(u << 16);
}
__device__ __forceinline__ void gload16(const void* g, void* l) {
  __builtin_amdgcn_global_load_lds(
      (const __attribute__((address_space(1))) void*)g,
      (__attribute__((address_space(3))) void*)l, 16, 0, 0);
}

// ---------- 0: sniff input dtype ----------
__global__ void k_sniff(const void* x, int* flag) {
  __shared__ int cnt;
  int t = threadIdx.x;
  if (t == 0) cnt = 0;
  __syncthreads();
  const unsigned short* h = (const unsigned short*)x;
  int local = 0;
  for (int i = t; i < 4096; i += 256) {
    int e = (h[i] >> 7) & 0xFF;
    if (e >= 107 && e <= 133) local++;
  }
  atomicAdd(&cnt, local);
  __syncthreads();
  if (t == 0) *flag = (cnt >= 3482) ? 1 : 0;
}

// ---------- 1: histogram of dst ----------
__global__ void k_hist(const int* __restrict__ dst, int* __restrict__ cnt, int ne) {
  int e = blockIdx.x * 256 + threadIdx.x;
  if (e < ne) atomicAdd(&cnt[dst[e]], 1);
}

// ---------- 2a: per-chunk exclusive scan ----------
__global__ void k_scan1(const int* __restrict__ cnt, int* __restrict__ off,
                        int* __restrict__ partials, int n) {
  __shared__ int s[1024];
  int t = threadIdx.x;
  int idx = blockIdx.x * 1024 + t;
  int v = (idx < n) ? cnt[idx] : 0;
  s[t] = v;
  __syncthreads();
  for (int d = 1; d < 1024; d <<= 1) {
    int tmp = (t >= d) ? s[t - d] : 0;
    __syncthreads();
    s[t] += tmp;
    __syncthreads();
  }
  if (idx < n) off[idx] = s[t] - v;
  if (t == 1023) partials[blockIdx.x] = s[1023];
}

// ---------- 2b: scan chunk totals ----------
__global__ void k_scan2(const int* __restrict__ partials, int* __restrict__ pref,
                        int* __restrict__ off, int nb, int npos) {
  __shared__ int s[128];
  int t = threadIdx.x;
  int v = (t < nb) ? partials[t] : 0;
  s[t] = v;
  __syncthreads();
  for (int d = 1; d < 128; d <<= 1) {
    int tmp = (t >= d) ? s[t - d] : 0;
    __syncthreads();
    s[t] += tmp;
    __syncthreads();
  }
  if (t < nb) pref[t] = s[t] - v;
  if (t == 127) off[npos] = s[127];
}

// ---------- 2c: apply chunk prefixes ----------
__global__ void k_scan3(int* __restrict__ off, const int* __restrict__ pref,
                        int* __restrict__ cursor, int n) {
  int i = blockIdx.x * 256 + threadIdx.x;
  if (i < n) {
    int o = off[i] + pref[i >> 10];
    off[i] = o;
    cursor[i] = o;
  }
}

// ---------- 3: bucket fill -> fused 16B edge record {src, m_lo, m_hi, 0} ----------
__global__ void k_fill(const int* __restrict__ ei,
                       const void* nr, const void* ni, const void* nj, const void* nk,
                       const int* __restrict__ flagp, int* __restrict__ cursor,
                       uint4* __restrict__ recs, int ne) {
  int isbf = *flagp;
  int e = blockIdx.x * 256 + threadIdx.x;
  if (e >= ne) return;
  int s = ei[e];
  int d = ei[ne + e];
  int pos = atomicAdd(&cursor[d], 1);
  uint4 r;
  r.x = (unsigned)s;
  r.y = (unsigned)f2b(-ldf(nr, e, isbf)) | ((unsigned)f2b(-ldf(ni, e, isbf)) << 16);
  r.z = (unsigned)f2b(-ldf(nj, e, isbf)) | ((unsigned)f2b(-ldf(nk, e, isbf)) << 16);
  r.w = 0;
  recs[pos] = r;
}

// ---------- 3b: interleave inputs -> Xg[node][feat][comp] bf16 ----------
__global__ __launch_bounds__(256) void k_ilv(
    const void* X0, const void* X1, const void* X2, const void* X3,
    const int* __restrict__ flagp, unsigned short* __restrict__ Xg, int n) {
  int isbf = *flagp;
  int lane = threadIdx.x & 63;
  int node = blockIdx.x * 4 + (threadIdx.x >> 6);
  if (node >= n) return;
  int idx = node * 64 + lane;
  unsigned int lo = f2b(ldf(X0, idx, isbf)) | ((unsigned int)f2b(ldf(X1, idx, isbf)) << 16);
  unsigned int hi = f2b(ldf(X2, idx, isbf)) | ((unsigned int)f2b(ldf(X3, idx, isbf)) << 16);
  uint2 g = make_uint2(lo, hi);
  *(uint2*)(Xg + (size_t)node * 256 + lane * 4) = g;
}

// ---------- 4: quaternion aggregation (wave/node, scalar metadata path) ----------
// node forced wave-uniform via readfirstlane -> CSR bounds + record loads are
// scalar; m unpack in SALU; gather base in SALU (0 VALU addressing).
// Output: fragment-major Tf[(node>>4)*4096 + kc*512 + q*128 + (node&15)*8 + j]
__global__ __launch_bounds__(256, 8) void k_agg(
    const unsigned short* __restrict__ Xg, const int* __restrict__ off,
    const uint4* __restrict__ recs, unsigned short* __restrict__ Tf, int nnodes) {
  __shared__ unsigned short tl[4][256];
  int lane = threadIdx.x & 63;
  int w = threadIdx.x >> 6;
  int node = __builtin_amdgcn_readfirstlane(blockIdx.x * 4 + w);
  if (node >= nnodes) return;
  int rs = off[node], re = off[node + 1];
  float tr = 0.f, ti = 0.f, tj = 0.f, tk = 0.f;

  auto qacc = [&](uint2 g, unsigned mx, unsigned my) {
    float mr = __uint_as_float(mx << 16), mi = __uint_as_float(mx & 0xffff0000u);
    float mj = __uint_as_float(my << 16), mk = __uint_as_float(my & 0xffff0000u);
    float xr = __uint_as_float(g.x << 16), xi = __uint_as_float(g.x & 0xffff0000u);
    float xj = __uint_as_float(g.y << 16), xk = __uint_as_float(g.y & 0xffff0000u);
    tr += mr * xr - mi * xi - mj * xj - mk * xk;
    ti += mr * xi + mi * xr + mj * xk - mk * xj;
    tj += mr * xj - mi * xk + mj * xr + mk * xi;
    tk += mr * xk + mi * xj - mj * xi + mk * xr;
  };

  int e = rs;
  for (; e + 8 <= re; e += 8) {
    int ss[8];
    unsigned sx[8], sy[8];
#pragma unroll
    for (int u = 0; u < 8; u++) {
      uint4 r = recs[e + u];  // uniform address
      ss[u] = __builtin_amdgcn_readfirstlane((int)r.x);
      sx[u] = __builtin_amdgcn_readfirstlane(r.y);
      sy[u] = __builtin_amdgcn_readfirstlane(r.z);
    }
    uint2 g[8];
#pragma unroll
    for (int u = 0; u < 8; u++)
      g[u] = *(const uint2*)(Xg + (size_t)ss[u] * 256 + lane * 4);  // SGPR base + lane off
#pragma unroll
    for (int u = 0; u < 8; u++) qacc(g[u], sx[u], sy[u]);
  }
  for (; e < re; ++e) {
    uint4 r = recs[e];
    int s = __builtin_amdgcn_readfirstlane((int)r.x);
    unsigned mx = __builtin_amdgcn_readfirstlane(r.y);
    unsigned my = __builtin_amdgcn_readfirstlane(r.z);
    uint2 g0 = *(const uint2*)(Xg + (size_t)s * 256 + lane * 4);
    qacc(g0, mx, my);
  }

  // in-wave transpose: lane=f holds 4 comps -> 16B chunks in k-order
  tl[w][lane] = f2b(tr);
  tl[w][64 + lane] = f2b(ti);
  tl[w][128 + lane] = f2b(tj);
  tl[w][192 + lane] = f2b(tk);
  __builtin_amdgcn_wave_barrier();
  if (lane < 32) {
    uint4 v = *(const uint4*)&tl[w][lane * 8];
    size_t o = (size_t)(node >> 4) * 4096 + (lane >> 2) * 512 + (lane & 3) * 128 +
               (node & 15) * 8;
    *(uint4*)(Tf + o) = v;
  }
}

// ---------- 5: build swizzled k-major base matrices Wq (4x64x64, 32KB) + bias ----------
// Wq[(w4*64 + h)*64 + ((kk>>3)^(h&7))*8 + (kk&7)] = W[w4][kk][h]  (bf16, NO sign)
__global__ void k_weff(const void* W, const void* b, const int* __restrict__ flagp,
                       unsigned short* __restrict__ Wq, float* __restrict__ bcat) {
  int isbf = *flagp;
  int t = blockIdx.x * 256 + threadIdx.x;  // 0..16383
  int w4 = t >> 12;
  int h = (t >> 6) & 63;
  int kk = t & 63;
  int s = (kk >> 3) ^ (h & 7);
  Wq[(w4 * 64 + h) * 64 + s * 8 + (kk & 7)] = f2b(ldf(W, w4 * 4096 + kk * 64 + h, isbf));
  if (t < 256) bcat[t] = ldf(b, t, isbf);
}

// ---------- 6: quaternion-structured MFMA GEMM, one barrier (unchanged R6) ----------
__global__ __launch_bounds__(256, 2) void k_gemm(
    const unsigned short* __restrict__ A, const unsigned short* __restrict__ Wq,
    const float* __restrict__ bias, int M, int mode,
    unsigned short* __restrict__ XgOut,
    float* __restrict__ P, const void* Cw, const int* __restrict__ flagp) {
  __shared__ unsigned short Wsm[16384];  // 32 KB

  int t = threadIdx.x;
  int lane = t & 63;
  int w = t >> 6;
  int l15 = lane & 15, quad = lane >> 4;
  int m0 = blockIdx.x * 64;
  int hh = (w & 1) * 32;

#pragma unroll
  for (int i = 0; i < 8; i++)
    gload16((const char*)Wq + (size_t)(i * 256 + t) * 16,
            (char*)Wsm + (size_t)(i * 256 + w * 64) * 16);
  __syncthreads();

  short8 av[2][8];
  int n16 = blockIdx.x * 4 + (w >> 1) * 2;
#pragma unroll
  for (int mi = 0; mi < 2; mi++)
#pragma unroll
    for (int kc = 0; kc < 8; kc++)
      av[mi][kc] = *(const short8*)(A + (size_t)(n16 + mi) * 4096 + kc * 512 + lane * 8);

  f32x4 acc[2][4][2];
#pragma unroll
  for (int mi = 0; mi < 2; mi++)
#pragma unroll
    for (int c = 0; c < 4; c++)
#pragma unroll
      for (int hb = 0; hb < 2; hb++) acc[mi][c][hb] = (f32x4){0.f, 0.f, 0.f, 0.f};

#pragma unroll
  for (int kc = 0; kc < 8; kc++) {
    int a = kc >> 1;
    short8 bv[4][2];
#pragma unroll
    for (int c = 0; c < 4; c++) {
      int w4 = a ^ c;
      int neg = (0x3950 >> (a * 4 + c)) & 1;
#pragma unroll
      for (int hb = 0; hb < 2; hb++) {
        int h = hh + hb * 16 + l15;
        int lc = ((kc & 1) * 4 + quad) ^ (l15 & 7);
        short8 bb = *(const short8*)&Wsm[(w4 * 64 + h) * 64 + lc * 8];
        if (neg) {
          uint4 u = *(uint4*)&bb;
          u.x ^= 0x80008000u; u.y ^= 0x80008000u;
          u.z ^= 0x80008000u; u.w ^= 0x80008000u;
          bb = *(short8*)&u;
        }
        bv[c][hb] = bb;
      }
    }
#pragma unroll
    for (int mi = 0; mi < 2; mi++)
#pragma unroll
      for (int c = 0; c < 4; c++)
#pragma unroll
        for (int hb = 0; hb < 2; hb++)
          acc[mi][c][hb] =
              __builtin_amdgcn_mfma_f32_16x16x32_bf16(av[mi][kc], bv[c][hb], acc[mi][c][hb], 0, 0, 0);
  }

  float bias_v[4][2];
#pragma unroll
  for (int c = 0; c < 4; c++)
#pragma unroll
    for (int hb = 0; hb < 2; hb++) bias_v[c][hb] = bias[c * 64 + hh + hb * 16 + l15];

  if (mode == 0) {
#pragma unroll
    for (int mi = 0; mi < 2; mi++) {
#pragma unroll
      for (int hb = 0; hb < 2; hb++) {
#pragma unroll
        for (int r = 0; r < 4; r++) {
          int node = m0 + (w >> 1) * 32 + mi * 16 + quad * 4 + r;
          unsigned int lo =
              f2b(fmaxf(acc[mi][0][hb][r] + bias_v[0][hb], 0.f)) |
              ((unsigned int)f2b(fmaxf(acc[mi][1][hb][r] + bias_v[1][hb], 0.f)) << 16);
          unsigned int hi =
              f2b(fmaxf(acc[mi][2][hb][r] + bias_v[2][hb], 0.f)) |
              ((unsigned int)f2b(fmaxf(acc[mi][3][hb][r] + bias_v[3][hb], 0.f)) << 16);
          *(uint2*)(XgOut + (size_t)node * 256 + (hh + hb * 16 + l15) * 4) =
              make_uint2(lo, hi);
        }
      }
    }
  } else {
    int isbf = *flagp;
    float cw[4][2][4];
#pragma unroll
    for (int c = 0; c < 4; c++)
#pragma unroll
      for (int hb = 0; hb < 2; hb++) {
        int h = hh + hb * 16 + l15;
#pragma unroll
        for (int d = 0; d < 2; d++)
#pragma unroll
          for (int e = 0; e < 2; e++)
            cw[c][hb][e + 2 * d] = ldf(Cw, d * 512 + c * 128 + e * 64 + h, isbf);
      }
#pragma unroll
    for (int mi = 0; mi < 2; mi++) {
#pragma unroll
      for (int r = 0; r < 4; r++) {
        int node = m0 + (w >> 1) * 32 + mi * 16 + quad * 4 + r;
        float pd0 = 0.f, pd1 = 0.f, pd2 = 0.f, pd3 = 0.f;
#pragma unroll
        for (int c = 0; c < 4; c++)
#pragma unroll
          for (int hb = 0; hb < 2; hb++) {
            float v = fmaxf(acc[mi][c][hb][r] + bias_v[c][hb], 0.f);
            pd0 += v * cw[c][hb][0];
            pd1 += v * cw[c][hb][1];
            pd2 += v * cw[c][hb][2];
            pd3 += v * cw[c][hb][3];
          }
#pragma unroll
        for (int o = 1; o < 16; o <<= 1) {
          pd0 += __shfl_xor(pd0, o);
          pd1 += __shfl_xor(pd1, o);
          pd2 += __shfl_xor(pd2, o);
          pd3 += __shfl_xor(pd3, o);
        }
        if (l15 == 0 && node < M) {
          atomicAdd(&P[node * 4 + 0], pd0);
          atomicAdd(&P[node * 4 + 1], pd1);
          atomicAdd(&P[node * 4 + 2], pd2);
          atomicAdd(&P[node * 4 + 3], pd3);
        }
      }
    }
  }
}

// ---------- 8: per-query logits + log_softmax ----------
__global__ void k_query(const int* __restrict__ qe, const float* __restrict__ P,
                        const void* Cb, const int* __restrict__ flagp,
                        void* out, int nq) {
  int isbf = *flagp;
  int q = blockIdx.x * 256 + threadIdx.x;
  if (q >= nq) return;
  int q0 = qe[q * 2], q1 = qe[q * 2 + 1];
  float l0 = P[q0 * 4 + 0] + P[q1 * 4 + 1] + ldf(Cb, 0, isbf);
  float l1 = P[q0 * 4 + 2] + P[q1 * 4 + 3] + ldf(Cb, 1, isbf);
  float m = fmaxf(l0, l1);
  float lse = m + logf(expf(l0 - m) + expf(l1 - m));
  float o0 = l0 - lse, o1 = l1 - lse;
  if (isbf) {
    __hip_bfloat16* o = (__hip_bfloat16*)out;
    o[q * 2] = __float2bfloat16(o0);
    o[q * 2 + 1] = __float2bfloat16(o1);
  } else {
    float* o = (float*)out;
    o[q * 2] = o0;
    o[q * 2 + 1] = o1;
  }
}

extern "C" void kernel_launch(void* const* d_in, const int* in_sizes, int n_in,
                              void* d_out, int out_size, void* d_ws, size_t ws_size,
                              hipStream_t stream) {
  const int N = N_NODESC, NE = N_EDGESC, NQ = N_QUERYC;
  const int NPAD = 100224;  // >= 1563*64 = 100032

  char* w = (char*)d_ws;
  auto alloc = [&](size_t bytes) -> void* {
    void* p = (void*)w;
    w += (bytes + 255) & ~(size_t)255;
    return p;
  };
  int* flag       = (int*)alloc(4);
  int* offsets    = (int*)alloc((size_t)(N + 1) * 4);
  int* cursor     = (int*)alloc((size_t)N * 4);
  int* partials   = (int*)alloc(128 * 4);
  int* pref       = (int*)alloc(128 * 4);
  uint4* recs     = (uint4*)alloc((size_t)NE * 16);
  unsigned short* Tf = (unsigned short*)alloc((size_t)NPAD * 256 * 2);
  unsigned short* Xg = (unsigned short*)alloc((size_t)NPAD * 256 * 2);
  unsigned short* Wq = (unsigned short*)alloc(16384 * 2);
  float* bcat     = (float*)alloc(256 * 4);
  float* P        = (float*)alloc((size_t)N * 4 * 4);
  (void)ws_size; (void)n_in; (void)in_sizes; (void)out_size;

  const int* ei = (const int*)d_in[8];

  k_sniff<<<1, 256, 0, stream>>>(d_in[0], flag);

  // CSR build
  hipMemsetAsync(cursor, 0, (size_t)N * 4, stream);
  hipMemsetAsync(P, 0, (size_t)N * 16, stream);
  k_hist<<<(NE + 255) / 256, 256, 0, stream>>>(ei + NE, cursor, NE);
  k_scan1<<<(N + 1023) / 1024, 1024, 0, stream>>>(cursor, offsets, partials, N);
  k_scan2<<<1, 128, 0, stream>>>(partials, pref, offsets, (N + 1023) / 1024, N);
  k_scan3<<<(N + 255) / 256, 256, 0, stream>>>(offsets, pref, cursor, N);
  k_fill<<<(NE + 255) / 256, 256, 0, stream>>>(ei, d_in[4], d_in[5], d_in[6], d_in[7],
                                               flag, cursor, recs, NE);

  // layer-1 gather source
  k_ilv<<<(N + 3) / 4, 256, 0, stream>>>(d_in[0], d_in[1], d_in[2], d_in[3], flag, Xg, N);

  int ggrid = (N + 63) / 64;

  // layer 1
  k_agg<<<(N + 3) / 4, 256, 0, stream>>>(Xg, offsets, recs, Tf, N);
  k_weff<<<64, 256, 0, stream>>>(d_in[10], d_in[11], flag, Wq, bcat);
  k_gemm<<<ggrid, 256, 0, stream>>>(Tf, Wq, bcat, N, 0, Xg, nullptr, nullptr, flag);

  // layer 2 (+fused readout partial dots)
  k_agg<<<(N + 3) / 4, 256, 0, stream>>>(Xg, offsets, recs, Tf, N);
  k_weff<<<64, 256, 0, stream>>>(d_in[12], d_in[13], flag, Wq, bcat);
  k_gemm<<<ggrid, 256, 0, stream>>>(Tf, Wq, bcat, N, 1, nullptr, P, d_in[14], flag);

  // queries
  k_query<<<(NQ + 255) / 256, 256, 0, stream>>>((const int*)d_in[9], P, d_in[15],
                                                flag, d_out, NQ);
}